// Round 1
// baseline (571.904 us; speedup 1.0000x reference)
//
#include <hip/hip_runtime.h>

#define B   32
#define IDF 768
#define CDF 768
#define SL  128
#define QL  1024

// -----------------------------------------------------------------------------
// Kernel 1: S[b][o][s] = sum_c W[o][c] * ctx[b][c][s]   (sourceT projection)
// block = 128 threads (t = s), o-tile = 32, K tiled by 128 via LDS
// -----------------------------------------------------------------------------
__global__ __launch_bounds__(128) void proj_kernel(const float* __restrict__ ctx,
                                                   const float* __restrict__ W,
                                                   float* __restrict__ S) {
  const int b  = blockIdx.y;
  const int o0 = blockIdx.x * 32;
  const int t  = threadIdx.x;  // s index
  float acc[32];
#pragma unroll
  for (int o = 0; o < 32; ++o) acc[o] = 0.f;
  __shared__ float Wl[32][128];
  for (int c0 = 0; c0 < CDF; c0 += 128) {
#pragma unroll
    for (int k = 0; k < 32; ++k) Wl[k][t] = W[(size_t)(o0 + k) * CDF + c0 + t];
    __syncthreads();
    const float* cp = ctx + ((size_t)b * CDF + c0) * SL + t;
    for (int c = 0; c < 128; ++c) {
      float v = cp[(size_t)c * SL];
#pragma unroll
      for (int o = 0; o < 32; ++o) acc[o] = fmaf(Wl[o][c], v, acc[o]);
    }
    __syncthreads();
  }
#pragma unroll
  for (int o = 0; o < 32; ++o) S[((size_t)b * IDF + o0 + o) * SL + t] = acc[o];
}

// -----------------------------------------------------------------------------
// Kernel 2: A[q][s] = sum_i input[b][i][q] * S[b][i][s]; mask; softmax over s;
//           write softmaxed A to ws ([b][q][s]) and attn_out ([b][s][q]).
// block = 128 threads (t = s), q-tile = 32
// -----------------------------------------------------------------------------
__global__ __launch_bounds__(128) void attn_kernel(const float* __restrict__ input,
                                                   const float* __restrict__ S,
                                                   const int* __restrict__ mask,
                                                   float* __restrict__ A_ws,
                                                   float* __restrict__ attn_out) {
  const int b  = blockIdx.y;
  const int q0 = blockIdx.x * 32;
  const int t  = threadIdx.x;  // s index
  float acc[32];
#pragma unroll
  for (int q = 0; q < 32; ++q) acc[q] = 0.f;
  __shared__ float Tl[128][32];
  for (int i0 = 0; i0 < IDF; i0 += 128) {
#pragma unroll
    for (int k = 0; k < 32; ++k) {
      int idx = k * 128 + t;
      int i = idx >> 5, q = idx & 31;
      Tl[i][q] = input[((size_t)b * IDF + i0 + i) * QL + q0 + q];
    }
    __syncthreads();
    const float* sp = S + ((size_t)b * IDF + i0) * SL + t;
    for (int i = 0; i < 128; ++i) {
      float sv = sp[(size_t)i * SL];
#pragma unroll
      for (int q = 0; q < 32; ++q) acc[q] = fmaf(Tl[i][q], sv, acc[q]);
    }
    __syncthreads();
  }
  // mask add, transpose into LDS as [q][s]
  __shared__ float Al[32][129];
  const float madd = -10000.0f * (float)mask[b * SL + t];
#pragma unroll
  for (int q = 0; q < 32; ++q) Al[q][t] = acc[q] + madd;
  __syncthreads();

  // softmax over s per row q; 4 threads per row, 32 elements each
  const int row = t >> 2, t4 = t & 3;
  __shared__ float red[32][4];
  float mx = -1e30f;
#pragma unroll
  for (int k = 0; k < 32; ++k) mx = fmaxf(mx, Al[row][t4 * 32 + k]);
  red[row][t4] = mx;
  __syncthreads();
  mx = fmaxf(fmaxf(red[row][0], red[row][1]), fmaxf(red[row][2], red[row][3]));
  __syncthreads();  // all reads of red done before reuse
  float sum = 0.f;
#pragma unroll
  for (int k = 0; k < 32; ++k) {
    float e = __expf(Al[row][t4 * 32 + k] - mx);
    Al[row][t4 * 32 + k] = e;
    sum += e;
  }
  red[row][t4] = sum;
  __syncthreads();
  const float inv = 1.0f / (red[row][0] + red[row][1] + red[row][2] + red[row][3]);
#pragma unroll
  for (int k = 0; k < 32; ++k) Al[row][t4 * 32 + k] *= inv;
  __syncthreads();

  // write softmaxed A to workspace [b][q][s] (coalesced over t=s)
#pragma unroll
  for (int q = 0; q < 32; ++q) A_ws[((size_t)b * QL + q0 + q) * SL + t] = Al[q][t];
  // write attn_out [b][s][q] (coalesced 32-wide chunks over q)
#pragma unroll
  for (int k = 0; k < 32; ++k) {
    int idx = k * 128 + t;
    int s = idx >> 5, q = idx & 31;
    attn_out[((size_t)b * SL + s) * QL + q0 + q] = Al[q][s];
  }
}

// -----------------------------------------------------------------------------
// Kernel 3: wc[b][i][q] = sum_s S[b][i][s] * A[b][q][s]
// block = 256 threads: q-tile 64 (lane = q), i-tile 32 (4 groups of 8)
// -----------------------------------------------------------------------------
__global__ __launch_bounds__(256) void pv_kernel(const float* __restrict__ S,
                                                 const float* __restrict__ A_ws,
                                                 float* __restrict__ wc) {
  const int b  = blockIdx.z;
  const int i0 = blockIdx.y * 32;
  const int q0 = blockIdx.x * 64;
  const int t  = threadIdx.x;
  __shared__ float Alds[64][129];
  __shared__ float Sl[32][129];
#pragma unroll
  for (int k = 0; k < 32; ++k) {
    int idx = k * 256 + t;
    int q = idx >> 7, s = idx & 127;
    Alds[q][s] = A_ws[((size_t)b * QL + q0 + q) * SL + s];
  }
#pragma unroll
  for (int k = 0; k < 16; ++k) {
    int idx = k * 256 + t;
    int i = idx >> 7, s = idx & 127;
    Sl[i][s] = S[((size_t)b * IDF + i0 + i) * SL + s];
  }
  __syncthreads();
  const int q = t & 63, ig = t >> 6;  // ig in 0..3, same for all lanes of a wave
  float acc[8];
#pragma unroll
  for (int j = 0; j < 8; ++j) acc[j] = 0.f;
  for (int s = 0; s < 128; ++s) {
    float av = Alds[q][s];
#pragma unroll
    for (int j = 0; j < 8; ++j) acc[j] = fmaf(Sl[ig * 8 + j][s], av, acc[j]);
  }
#pragma unroll
  for (int j = 0; j < 8; ++j)
    wc[((size_t)b * IDF + i0 + ig * 8 + j) * QL + q0 + q] = acc[j];
}

// -----------------------------------------------------------------------------
extern "C" void kernel_launch(void* const* d_in, const int* in_sizes, int n_in,
                              void* d_out, int out_size, void* d_ws, size_t ws_size,
                              hipStream_t stream) {
  const float* input   = (const float*)d_in[0];  // [B, IDF, 32, 32]
  const float* context = (const float*)d_in[1];  // [B, CDF, SL]
  const int*   mask    = (const int*)d_in[2];    // [B, SL]
  const float* w_conv  = (const float*)d_in[3];  // [IDF, CDF]

  float* out      = (float*)d_out;
  float* wc       = out;                              // [B, IDF, QL]
  float* attn_out = out + (size_t)B * IDF * QL;       // [B, SL, QL]

  float* S    = (float*)d_ws;                         // [B, IDF, SL] fp32
  float* A_ws = S + (size_t)B * IDF * SL;             // [B, QL, SL] fp32
  // workspace bytes needed: (B*IDF*SL + B*QL*SL)*4 = 29,360,128 B

  proj_kernel<<<dim3(IDF / 32, B), 128, 0, stream>>>(context, w_conv, S);
  attn_kernel<<<dim3(QL / 32, B), 128, 0, stream>>>(input, S, mask, A_ws, attn_out);
  pv_kernel<<<dim3(QL / 64, IDF / 32, B), 256, 0, stream>>>(S, A_ws, wc);
}

// Round 2
// 185.122 us; speedup vs baseline: 3.0893x; 3.0893x over previous
//
#include <hip/hip_runtime.h>

#define NB  32
#define IDF 768
#define SLN 128
#define QLN 1024

typedef __bf16 v8bf __attribute__((ext_vector_type(8)));
typedef __bf16 v4bf __attribute__((ext_vector_type(4)));
typedef float  v4f  __attribute__((ext_vector_type(4)));

#define MFMA __builtin_amdgcn_mfma_f32_16x16x32_bf16

__device__ __forceinline__ void split2(float x, __bf16& h, __bf16& l) {
  h = (__bf16)x;
  l = (__bf16)(x - (float)h);
}

// -----------------------------------------------------------------------------
// proj: D[s][o] = sum_c ctx[b][c][s] * W[o][c]   (= sourceT[o][s], transposed)
// A-operand = ctx^T [s][c] (scatter-split-staged), B-operand = W [o][c] (direct)
// Writes ST hi/lo [b][s][768] (for QK) and S hi [b][i][s] (for PV).
// block 256 = 4 waves; M=s=128 (8 frag rows), N=o tile 64 (1 frag col / wave)
// -----------------------------------------------------------------------------
__global__ __launch_bounds__(256) void proj_k(const float* __restrict__ ctx,
                                              const float* __restrict__ W,
                                              __bf16* __restrict__ STh,
                                              __bf16* __restrict__ STl,
                                              __bf16* __restrict__ Sh) {
  const int b = blockIdx.y, o0 = blockIdx.x * 64;
  const int t = threadIdx.x, w = t >> 6, lane = t & 63;
  const int lg = lane >> 4, lr = lane & 15;
  __shared__ __bf16 Ah[128][40], Al[128][40];  // ctxT [s][c-tile]
  __shared__ __bf16 Bh[64][40],  Bl[64][40];   // W   [o-tile][c-tile]
  v4f acc[8];
#pragma unroll
  for (int i = 0; i < 8; ++i) acc[i] = (v4f){0.f, 0.f, 0.f, 0.f};

  const int ac = t >> 3, aslo = t & 7;        // A-stage: c row, s lane
  const int bo = t >> 2, bcc = (t & 3) * 8;   // B-stage: o row, c chunk

  for (int c0 = 0; c0 < IDF; c0 += 32) {
    __syncthreads();
    // stage A (transpose + split): ctx[b][c0+ac][s] -> Ah/Al[s][ac]
    const float* ap = ctx + ((size_t)b * IDF + c0 + ac) * SLN;
#pragma unroll
    for (int e = 0; e < 16; ++e) {
      int s = aslo + e * 8;
      __bf16 h, l; split2(ap[s], h, l);
      Ah[s][ac] = h; Al[s][ac] = l;
    }
    // stage B (split, contiguous): W[o0+bo][c0+bcc..+8]
    const float* bp = W + (size_t)(o0 + bo) * IDF + c0 + bcc;
    float4 w0 = *(const float4*)bp, w1 = *(const float4*)(bp + 4);
    float tmp[8] = {w0.x, w0.y, w0.z, w0.w, w1.x, w1.y, w1.z, w1.w};
#pragma unroll
    for (int e = 0; e < 8; ++e) {
      __bf16 h, l; split2(tmp[e], h, l);
      Bh[bo][bcc + e] = h; Bl[bo][bcc + e] = l;
    }
    __syncthreads();
    v8bf bh = *(const v8bf*)&Bh[w * 16 + lr][lg * 8];
    v8bf bl = *(const v8bf*)&Bl[w * 16 + lr][lg * 8];
#pragma unroll
    for (int fr = 0; fr < 8; ++fr) {
      v8bf ah = *(const v8bf*)&Ah[fr * 16 + lr][lg * 8];
      v8bf al = *(const v8bf*)&Al[fr * 16 + lr][lg * 8];
      acc[fr] = MFMA(ah, bh, acc[fr], 0, 0, 0);
      acc[fr] = MFMA(ah, bl, acc[fr], 0, 0, 0);
      acc[fr] = MFMA(al, bh, acc[fr], 0, 0, 0);
    }
  }
  const int o = o0 + w * 16 + lr;
#pragma unroll
  for (int fr = 0; fr < 8; ++fr) {
    __bf16 hp[4];
#pragma unroll
    for (int r = 0; r < 4; ++r) {
      int s = fr * 16 + lg * 4 + r;
      float v = acc[fr][r];
      __bf16 h, l; split2(v, h, l);
      STh[((size_t)b * SLN + s) * IDF + o] = h;  // coalesced over lanes (o)
      STl[((size_t)b * SLN + s) * IDF + o] = l;
      hp[r] = h;
    }
    // S[b][i=o][s]: 4 consecutive s -> one 8B store
    *(v4bf*)&Sh[((size_t)b * IDF + o) * SLN + fr * 16 + lg * 4] =
        (v4bf){hp[0], hp[1], hp[2], hp[3]};
  }
}

// -----------------------------------------------------------------------------
// qk: L[s][q] = sum_i ST[s][i] * input[b][i][q]; +mask[s]; softmax over s;
//     writes attn_out[b][s][q] (f32, coalesced) and Apv[b][q][s] (bf16).
// A = ST [s][i] hi/lo (direct), B = input^T [q][i] hi/lo (scatter-split-staged)
// -----------------------------------------------------------------------------
__global__ __launch_bounds__(256) void qk_k(const float* __restrict__ input,
                                            const __bf16* __restrict__ STh,
                                            const __bf16* __restrict__ STl,
                                            const int* __restrict__ mask,
                                            __bf16* __restrict__ Apv,
                                            float* __restrict__ attn_out) {
  const int b = blockIdx.y, q0 = blockIdx.x * 64;
  const int t = threadIdx.x, w = t >> 6, lane = t & 63;
  const int lg = lane >> 4, lr = lane & 15;
  __shared__ __bf16 Ah[128][40], Al[128][40];  // ST [s][i-tile]
  __shared__ __bf16 Bh[64][40],  Bl[64][40];   // input^T [q-tile][i-tile]
  __shared__ float mlds[128];
  if (t < 128) mlds[t] = -10000.0f * (float)mask[b * SLN + t];
  v4f acc[8];
#pragma unroll
  for (int i = 0; i < 8; ++i) acc[i] = (v4f){0.f, 0.f, 0.f, 0.f};

  const int as_ = t >> 2, aic = (t & 3) * 8;  // A copy: s row, i chunk
  const int bi = t >> 3, bqlo = t & 7;        // B-stage: i row, q lane

  for (int i0 = 0; i0 < IDF; i0 += 32) {
    __syncthreads();
#pragma unroll
    for (int p = 0; p < 2; ++p) {
      int s = as_ + p * 64;
      size_t g = ((size_t)b * SLN + s) * IDF + i0 + aic;
      *(uint4*)&Ah[s][aic] = *(const uint4*)(STh + g);
      *(uint4*)&Al[s][aic] = *(const uint4*)(STl + g);
    }
    const float* bp = input + ((size_t)b * IDF + i0 + bi) * QLN + q0;
#pragma unroll
    for (int e = 0; e < 8; ++e) {
      int q = bqlo + e * 8;
      __bf16 h, l; split2(bp[q], h, l);
      Bh[q][bi] = h; Bl[q][bi] = l;
    }
    __syncthreads();
    v8bf bh = *(const v8bf*)&Bh[w * 16 + lr][lg * 8];
    v8bf bl = *(const v8bf*)&Bl[w * 16 + lr][lg * 8];
#pragma unroll
    for (int fr = 0; fr < 8; ++fr) {
      v8bf ah = *(const v8bf*)&Ah[fr * 16 + lr][lg * 8];
      v8bf al = *(const v8bf*)&Al[fr * 16 + lr][lg * 8];
      acc[fr] = MFMA(ah, bh, acc[fr], 0, 0, 0);
      acc[fr] = MFMA(ah, bl, acc[fr], 0, 0, 0);
      acc[fr] = MFMA(al, bh, acc[fr], 0, 0, 0);
    }
  }
  // epilogue: lane owns q = q0+w*16+lr, holds 32 of the 128 s values
  const int q = q0 + w * 16 + lr;
  float mx = -3.0e38f;
#pragma unroll
  for (int fr = 0; fr < 8; ++fr)
#pragma unroll
    for (int r = 0; r < 4; ++r) {
      acc[fr][r] += mlds[fr * 16 + lg * 4 + r];
      mx = fmaxf(mx, acc[fr][r]);
    }
  mx = fmaxf(mx, __shfl_xor(mx, 16));
  mx = fmaxf(mx, __shfl_xor(mx, 32));
  float sum = 0.f;
#pragma unroll
  for (int fr = 0; fr < 8; ++fr)
#pragma unroll
    for (int r = 0; r < 4; ++r) {
      float e = __expf(acc[fr][r] - mx);
      acc[fr][r] = e;
      sum += e;
    }
  sum += __shfl_xor(sum, 16);
  sum += __shfl_xor(sum, 32);
  const float inv = 1.0f / sum;
#pragma unroll
  for (int fr = 0; fr < 8; ++fr) {
    __bf16 hp[4];
#pragma unroll
    for (int r = 0; r < 4; ++r) {
      float p = acc[fr][r] * inv;
      int s = fr * 16 + lg * 4 + r;
      attn_out[((size_t)b * SLN + s) * QLN + q] = p;  // coalesced over lanes
      hp[r] = (__bf16)p;
    }
    *(v4bf*)&Apv[((size_t)b * QLN + q) * SLN + fr * 16 + lg * 4] =
        (v4bf){hp[0], hp[1], hp[2], hp[3]};
  }
}

// -----------------------------------------------------------------------------
// pv: wc[i][q] = sum_s S[i][s] * Apv[q][s].  A = S[i][s], B = Apv[q][s], both
// direct bf16. Block tile 128i x 128q, K=128 staged once. 4 waves, 2x8 frags.
// -----------------------------------------------------------------------------
__global__ __launch_bounds__(256) void pv_k(const __bf16* __restrict__ Sh,
                                            const __bf16* __restrict__ Apv,
                                            float* __restrict__ wc) {
  const int b = blockIdx.z, i0 = blockIdx.y * 128, q0 = blockIdx.x * 128;
  const int t = threadIdx.x, w = t >> 6, lane = t & 63;
  const int lg = lane >> 4, lr = lane & 15;
  __shared__ __bf16 Sl[128][136];
  __shared__ __bf16 Bl[128][136];
#pragma unroll
  for (int p = 0; p < 8; ++p) {
    int idx = p * 256 + t;
    int row = idx >> 4, ch = (idx & 15) * 8;
    *(uint4*)&Sl[row][ch] = *(const uint4*)(Sh  + ((size_t)b * IDF + i0 + row) * SLN + ch);
    *(uint4*)&Bl[row][ch] = *(const uint4*)(Apv + ((size_t)b * QLN + q0 + row) * SLN + ch);
  }
  __syncthreads();
  v4f acc[2][8];
#pragma unroll
  for (int fr = 0; fr < 2; ++fr)
#pragma unroll
    for (int fc = 0; fc < 8; ++fc) acc[fr][fc] = (v4f){0.f, 0.f, 0.f, 0.f};
#pragma unroll
  for (int kt = 0; kt < 4; ++kt) {
    int k0 = kt * 32 + lg * 8;
    v8bf a0 = *(const v8bf*)&Sl[w * 32 + lr][k0];
    v8bf a1 = *(const v8bf*)&Sl[w * 32 + 16 + lr][k0];
#pragma unroll
    for (int fc = 0; fc < 8; ++fc) {
      v8bf bb = *(const v8bf*)&Bl[fc * 16 + lr][k0];
      acc[0][fc] = MFMA(a0, bb, acc[0][fc], 0, 0, 0);
      acc[1][fc] = MFMA(a1, bb, acc[1][fc], 0, 0, 0);
    }
  }
#pragma unroll
  for (int fr = 0; fr < 2; ++fr)
#pragma unroll
    for (int fc = 0; fc < 8; ++fc)
#pragma unroll
      for (int r = 0; r < 4; ++r) {
        int i = i0 + w * 32 + fr * 16 + lg * 4 + r;
        wc[((size_t)b * IDF + i) * QLN + q0 + fc * 16 + lr] = acc[fr][fc][r];
      }
}

// -----------------------------------------------------------------------------
extern "C" void kernel_launch(void* const* d_in, const int* in_sizes, int n_in,
                              void* d_out, int out_size, void* d_ws, size_t ws_size,
                              hipStream_t stream) {
  const float* input   = (const float*)d_in[0];  // [B, IDF, 32, 32]
  const float* context = (const float*)d_in[1];  // [B, CDF, SL]
  const int*   mask    = (const int*)d_in[2];    // [B, SL]
  const float* w_conv  = (const float*)d_in[3];  // [IDF, CDF]

  float* out      = (float*)d_out;
  float* wc       = out;                         // [B, IDF, QL]
  float* attn_out = out + (size_t)NB * IDF * QLN;

  // workspace: ST hi/lo [b][s][768], S hi [b][i][s], Apv [b][q][s]
  // bytes = (3*3145728 + 4194304)*2 = 27,262,976  (< 29,360,128 proven OK)
  __bf16* wsb = (__bf16*)d_ws;
  const size_t SE = (size_t)NB * SLN * IDF;  // 3,145,728
  __bf16* STh = wsb;
  __bf16* STl = STh + SE;
  __bf16* Shv = STl + SE;
  __bf16* Apv = Shv + SE;                    // NB*QLN*SLN = 4,194,304

  proj_k<<<dim3(12, NB), 256, 0, stream>>>(context, w_conv, STh, STl, Shv);
  qk_k<<<dim3(16, NB), 256, 0, stream>>>(input, STh, STl, mask, Apv, attn_out);
  pv_k<<<dim3(8, 6, NB), 256, 0, stream>>>(Shv, Apv, wc);
}